// Round 5
// baseline (249.564 us; speedup 1.0000x reference)
//
#include <hip/hip_runtime.h>

#define BATCH 512
#define NN    200
#define NG    2                 // graphs per block (persistent Rs)
#define NBLK  (BATCH / NG)      // 256 blocks, 1 per CU
#define SIG1  0.73105857863f    // sigmoid(1)
#define SIG0  0.5f              // sigmoid(0)
#define XOFF  40000             // float offset of x-buffers in smem (after Rs)
#define XPAD  208               // floats per x-buffer (200 used, 16B-aligned)
#define SMEM_BYTES ((XOFF + 3 * XPAD) * 4)   // 162,496 B of 163,840 pool

typedef unsigned int uint;

// ---------------------------------------------------------------------------
// prep: blocks 0..156: Rs[n][m] = 0.5*(R[n][m]+R[m][n]) + (n==m)   (fp32)
//       block 157:     Wc = W0 @ (W1 @ (W2 @ pw))   [200][2] fp32
// [Verbatim r0 prep — r0 had the best measured total.]
__global__ __launch_bounds__(256) void prep(
    const float* __restrict__ R,
    const float* __restrict__ W0, const float* __restrict__ W1,
    const float* __restrict__ W2, const float* __restrict__ pw,
    float* __restrict__ Rs, float* __restrict__ Wc) {
    const int blk = blockIdx.x;
    const int tid = threadIdx.x;
    if (blk < 157) {
        int idx = blk * 256 + tid;
        if (idx < NN * NN) {
            int n = idx / NN, m = idx - n * NN;
            Rs[idx] = 0.5f * (R[idx] + R[m * NN + n]) + (n == m ? 1.f : 0.f);
        }
    } else {
        __shared__ float t0[256], t1[256];
        float a0 = 0.f, a1 = 0.f;
#pragma unroll 16
        for (int c = 0; c < 256; ++c) {
            float w2 = W2[tid * 256 + c];
            a0 += w2 * pw[2 * c];
            a1 += w2 * pw[2 * c + 1];
        }
        t0[tid] = a0; t1[tid] = a1;
        __syncthreads();
        float b0 = 0.f, b1 = 0.f;
#pragma unroll 16
        for (int h = 0; h < 256; ++h) {
            float w1 = W1[tid * 256 + h];
            b0 += w1 * t0[h];
            b1 += w1 * t1[h];
        }
        __syncthreads();
        t0[tid] = b0; t1[tid] = b1;
        __syncthreads();
        if (tid < NN) {
            float c0 = 0.f, c1 = 0.f;
#pragma unroll 16
            for (int o = 0; o < 256; ++o) {
                float w0 = W0[tid * 256 + o];
                c0 += w0 * t0[o];
                c1 += w0 * t1[o];
            }
            Wc[tid * 2 + 0] = c0;
            Wc[tid * 2 + 1] = c1;
        }
    }
}

// ---------------------------------------------------------------------------
// Phase bodies. NR is compile-time (13 or 12), full unroll. No register
// array survives a barrier (r2 spill lesson).

// A (first graph): stream adj + global Rs, mirror Rs into LDS, build bitmasks.
template<int NR>
__device__ __forceinline__ void phA_first(const float* __restrict__ adjr,
                                          const float* __restrict__ rsr,
                                          float* __restrict__ rsl,
                                          uint& m0, uint& m1, uint& m2, uint& m3,
                                          float4& acc) {
#pragma unroll
    for (int j = 0; j < NR; ++j) {
        float4 r = *(const float4*)(rsr + j * NN);
        float4 a = *(const float4*)(adjr + j * NN);
        *(float4*)(rsl + j * NN) = r;
        bool t;
        t = a.x > 0.5f; m0 |= (uint)t << j; acc.x += r.x * (t ? SIG1 : SIG0);
        t = a.y > 0.5f; m1 |= (uint)t << j; acc.y += r.y * (t ? SIG1 : SIG0);
        t = a.z > 0.5f; m2 |= (uint)t << j; acc.z += r.z * (t ? SIG1 : SIG0);
        t = a.w > 0.5f; m3 |= (uint)t << j; acc.w += r.w * (t ? SIG1 : SIG0);
    }
}

// A (second graph): adj from global, Rs from LDS.
template<int NR>
__device__ __forceinline__ void phA_cached(const float* __restrict__ adjr,
                                           const float* __restrict__ rsl,
                                           uint& m0, uint& m1, uint& m2, uint& m3,
                                           float4& acc) {
#pragma unroll
    for (int j = 0; j < NR; ++j) {
        float4 r = *(const float4*)(rsl + j * NN);
        float4 a = *(const float4*)(adjr + j * NN);
        bool t;
        t = a.x > 0.5f; m0 |= (uint)t << j; acc.x += r.x * (t ? SIG1 : SIG0);
        t = a.y > 0.5f; m1 |= (uint)t << j; acc.y += r.y * (t ? SIG1 : SIG0);
        t = a.z > 0.5f; m2 |= (uint)t << j; acc.z += r.z * (t ? SIG1 : SIG0);
        t = a.w > 0.5f; m3 |= (uint)t << j; acc.w += r.w * (t ? SIG1 : SIG0);
    }
}

// B/C: acc += M^T x — Rs from LDS, bits in regs, x broadcast from LDS.
template<int NR>
__device__ __forceinline__ void phM(const float* __restrict__ rsl,
                                    const float* __restrict__ xr, int r0,
                                    uint m0, uint m1, uint m2, uint m3,
                                    float4& acc) {
#pragma unroll
    for (int j = 0; j < NR; ++j) {
        float4 r = *(const float4*)(rsl + j * NN);
        float xn = xr[r0 + j];
        acc.x += r.x * (((m0 >> j) & 1u) ? SIG1 : SIG0) * xn;
        acc.y += r.y * (((m1 >> j) & 1u) ? SIG1 : SIG0) * xn;
        acc.z += r.z * (((m2 >> j) & 1u) ? SIG1 : SIG0) * xn;
        acc.w += r.w * (((m3 >> j) & 1u) ? SIG1 : SIG0) * xn;
    }
}

// D: y partial over feat rows.
template<int NR>
__device__ __forceinline__ void phD(const float* __restrict__ fr,
                                    const float* __restrict__ xr, int r0,
                                    float4& acc) {
#pragma unroll
    for (int j = 0; j < NR; ++j) {
        float4 f = *(const float4*)(fr + j * NN);
        float xn = xr[r0 + j];
        acc.x += f.x * xn; acc.y += f.y * xn;
        acc.z += f.z * xn; acc.w += f.w * xn;
    }
}

// Epilogue: wave 0 dots y with Wc, shfl-reduces, writes out[2].
__device__ __forceinline__ void epilogue(const float* __restrict__ xE,
                                         const float* __restrict__ Wc,
                                         const float* __restrict__ pb,
                                         float* __restrict__ outp, int c4) {
    float p0 = 0.f, p1 = 0.f;
    if (c4 < 50) {
        float4 s = *(const float4*)(xE + c4 * 4);
        int c0i = c4 * 4;
        p0 = s.x * Wc[(c0i + 0) * 2] + s.y * Wc[(c0i + 1) * 2]
           + s.z * Wc[(c0i + 2) * 2] + s.w * Wc[(c0i + 3) * 2];
        p1 = s.x * Wc[(c0i + 0) * 2 + 1] + s.y * Wc[(c0i + 1) * 2 + 1]
           + s.z * Wc[(c0i + 2) * 2 + 1] + s.w * Wc[(c0i + 3) * 2 + 1];
    }
#pragma unroll
    for (int off = 32; off > 0; off >>= 1) {
        p0 += __shfl_down(p0, off);
        p1 += __shfl_down(p1, off);
    }
    if (c4 == 0) {
        outp[0] = p0 * (1.f / NN) + pb[0];
        outp[1] = p1 * (1.f / NN) + pb[1];
    }
}

// ---------------------------------------------------------------------------
// gcn_main: 256 blocks (1/CU), 1024 threads, 162.5 KB LDS.
// Block b handles graphs b and b+256 with Rs persistent in LDS:
// per-CU global loads drop from 1.6 MB to 800 KB (the measured ~25 GB/s/CU
// vector-load wall is the binding constraint).
// Per graph: A (adj stream, bitmasks, u) ; B, C (pure-LDS matvecs) ; D (feat
// stream, y) ; E (dot with Wc). Reductions via LDS atomicAdd into 3 rotating
// 200-float buffers; clamped lanes (c4>=50) zero the (p+1)%3 buffer each
// phase; one barrier per phase. Graph 0's epilogue overlaps graph 1's A.
__global__ __launch_bounds__(1024, 4) void gcn_main(
    const float* __restrict__ adj, const float* __restrict__ feat,
    const float* __restrict__ Rs, const float* __restrict__ Wc,
    const float* __restrict__ pb, float* __restrict__ out) {
    extern __shared__ float smem[];
    float* RsL = smem;                               // [200][200] fp32
    const int b0  = blockIdx.x;                      // 0..255
    const int tid = threadIdx.x;
    const int c4  = tid & 63;
    const int q   = tid >> 6;                        // 0..15, wave-uniform
    const int cc  = (c4 < 50) ? c4 : 49;
    const int col0 = cc * 4;
    const int r0  = (q < 8) ? 13 * q : 104 + 12 * (q - 8);
    const bool act = (c4 < 50);
    const int zid = q * 14 + (c4 - 50);              // zero-duty index (!act)

    if (tid < 3 * XPAD) smem[XOFF + tid] = 0.f;      // zero x0,x1,x2
    __syncthreads();

#pragma unroll
    for (int g = 0; g < NG; ++g) {
        const int pbase = 4 * g;                     // phase counter base
        const size_t gb = (size_t)(b0 + g * NBLK);
        const float* adjb  = adj  + gb * NN * NN;
        const float* featb = feat + gb * NN * NN;
        uint m0 = 0, m1 = 0, m2 = 0, m3 = 0;

        // ---- Phase A (p = pbase): u = M^T 1 ----
        {
            float* xw = smem + XOFF + ((pbase + 0) % 3) * XPAD;
            float* xz = smem + XOFF + ((pbase + 1) % 3) * XPAD;
            if (g > 0 && q == 0)   // epilogue of previous graph overlaps A
                epilogue(smem + XOFF + ((pbase + 2) % 3) * XPAD, Wc, pb,
                         out + (gb - NBLK) * 2, c4);
            float4 acc = {0.f, 0.f, 0.f, 0.f};
            if (act) {
                if (g == 0) {
                    if (q < 8) phA_first<13>(adjb + r0 * NN + col0,
                                             Rs + r0 * NN + col0,
                                             RsL + r0 * NN + col0,
                                             m0, m1, m2, m3, acc);
                    else       phA_first<12>(adjb + r0 * NN + col0,
                                             Rs + r0 * NN + col0,
                                             RsL + r0 * NN + col0,
                                             m0, m1, m2, m3, acc);
                } else {
                    if (q < 8) phA_cached<13>(adjb + r0 * NN + col0,
                                              RsL + r0 * NN + col0,
                                              m0, m1, m2, m3, acc);
                    else       phA_cached<12>(adjb + r0 * NN + col0,
                                              RsL + r0 * NN + col0,
                                              m0, m1, m2, m3, acc);
                }
                atomicAdd(&xw[col0 + 0], acc.x);
                atomicAdd(&xw[col0 + 1], acc.y);
                atomicAdd(&xw[col0 + 2], acc.z);
                atomicAdd(&xw[col0 + 3], acc.w);
            } else if (zid < XPAD) xz[zid] = 0.f;
            __syncthreads();
        }

        // ---- Phase B (p = pbase+1): v = M^T u ----
        {
            float* xw = smem + XOFF + ((pbase + 1) % 3) * XPAD;
            float* xr = smem + XOFF + ((pbase + 0) % 3) * XPAD;
            float* xz = smem + XOFF + ((pbase + 2) % 3) * XPAD;
            float4 acc = {0.f, 0.f, 0.f, 0.f};
            if (act) {
                if (q < 8) phM<13>(RsL + r0 * NN + col0, xr, r0, m0, m1, m2, m3, acc);
                else       phM<12>(RsL + r0 * NN + col0, xr, r0, m0, m1, m2, m3, acc);
                atomicAdd(&xw[col0 + 0], acc.x);
                atomicAdd(&xw[col0 + 1], acc.y);
                atomicAdd(&xw[col0 + 2], acc.z);
                atomicAdd(&xw[col0 + 3], acc.w);
            } else if (zid < XPAD) xz[zid] = 0.f;
            __syncthreads();
        }

        // ---- Phase C (p = pbase+2): w = M^T v ----
        {
            float* xw = smem + XOFF + ((pbase + 2) % 3) * XPAD;
            float* xr = smem + XOFF + ((pbase + 1) % 3) * XPAD;
            float* xz = smem + XOFF + ((pbase + 0) % 3) * XPAD;
            float4 acc = {0.f, 0.f, 0.f, 0.f};
            if (act) {
                if (q < 8) phM<13>(RsL + r0 * NN + col0, xr, r0, m0, m1, m2, m3, acc);
                else       phM<12>(RsL + r0 * NN + col0, xr, r0, m0, m1, m2, m3, acc);
                atomicAdd(&xw[col0 + 0], acc.x);
                atomicAdd(&xw[col0 + 1], acc.y);
                atomicAdd(&xw[col0 + 2], acc.z);
                atomicAdd(&xw[col0 + 3], acc.w);
            } else if (zid < XPAD) xz[zid] = 0.f;
            __syncthreads();
        }

        // ---- Phase D (p = pbase+3): y = X^T w ----
        {
            float* xw = smem + XOFF + ((pbase + 3) % 3) * XPAD;
            float* xr = smem + XOFF + ((pbase + 2) % 3) * XPAD;
            float* xz = smem + XOFF + ((pbase + 4) % 3) * XPAD;
            float4 acc = {0.f, 0.f, 0.f, 0.f};
            if (act) {
                if (q < 8) phD<13>(featb + r0 * NN + col0, xr, r0, acc);
                else       phD<12>(featb + r0 * NN + col0, xr, r0, acc);
                atomicAdd(&xw[col0 + 0], acc.x);
                atomicAdd(&xw[col0 + 1], acc.y);
                atomicAdd(&xw[col0 + 2], acc.z);
                atomicAdd(&xw[col0 + 3], acc.w);
            } else if (zid < XPAD) xz[zid] = 0.f;
            __syncthreads();
        }
    }

    // ---- Epilogue for last graph (reads buffer (4*NG+2)%3 = (8+2)%3 = 1) ----
    if (q == 0)
        epilogue(smem + XOFF + ((4 * NG + 2) % 3) * XPAD, Wc, pb,
                 out + (size_t)(b0 + NBLK) * 2, c4);
}

// ---------------------------------------------------------------------------
extern "C" void kernel_launch(void* const* d_in, const int* in_sizes, int n_in,
                              void* d_out, int out_size, void* d_ws, size_t ws_size,
                              hipStream_t stream) {
    const float* adj  = (const float*)d_in[0];
    const float* feat = (const float*)d_in[1];
    const float* R    = (const float*)d_in[2];
    const float* W0   = (const float*)d_in[3];
    const float* W1   = (const float*)d_in[4];
    const float* W2   = (const float*)d_in[5];
    const float* pw   = (const float*)d_in[6];
    const float* pb   = (const float*)d_in[7];

    char* ws = (char*)d_ws;
    float* Rs = (float*)(ws);             // 160,000 B
    float* Wc = (float*)(ws + 160000);    // 1,600 B

    static bool attr_done = false;
    if (!attr_done) {
        (void)hipFuncSetAttribute((const void*)gcn_main,
                                  hipFuncAttributeMaxDynamicSharedMemorySize,
                                  SMEM_BYTES);
        attr_done = true;
    }

    prep<<<158, 256, 0, stream>>>(R, W0, W1, W2, pw, Rs, Wc);
    gcn_main<<<NBLK, 1024, SMEM_BYTES, stream>>>(adj, feat, Rs, Wc, pb,
                                                 (float*)d_out);
}